// Round 2
// baseline (139.778 us; speedup 1.0000x reference)
//
#include <hip/hip_runtime.h>

#define IN_DIM 128
#define NB 5

// ---------------------------------------------------------------------------
// K1 (fused): per-node projection tables + basis scores + index-width probe
//   srcTab[n][0..4] = x[n].attn_w[k][0:128], [5] = x[n].scorer_w[0:128]
//   dstTab[n][0..4] = x[n].attn_w[k][128:256], [5] = x[n].scorer_w[128:256]
// 32 B packed rows (8 floats, slots 6,7 pad). 4 threads per node (dim-split).
// Last block instead computes bs[k]=dot(bases[k],scorer_w) and probes whether
// edge_index is int64 (stride 2) or int32 (stride 1).
// ---------------------------------------------------------------------------
__global__ __launch_bounds__(256) void proj_prep_kernel(
    const float* __restrict__ x,          // [N][128]
    const float* __restrict__ attn_w,     // [5][256]
    const float* __restrict__ scorer_w,   // [256]
    const float* __restrict__ bases,      // [5][256]
    const int*   __restrict__ eidx,       // index buffer viewed as int32
    float* __restrict__ srcTab,           // [N][8]
    float* __restrict__ dstTab,           // [N][8]
    float* __restrict__ bs,               // [5]
    int*   __restrict__ flag,             // stride (1 or 2)
    int n_nodes)
{
    const int t = threadIdx.x;

    if (blockIdx.x == gridDim.x - 1) {
        // ---- prep block ----
        // base scores: thread t covers dim t of all 5 bases
        float p[NB];
        #pragma unroll
        for (int k = 0; k < NB; ++k)
            p[k] = bases[k * 256 + t] * scorer_w[t];
        #pragma unroll
        for (int k = 0; k < NB; ++k) {
            #pragma unroll
            for (int off = 32; off > 0; off >>= 1)
                p[k] += __shfl_xor(p[k], off, 64);
        }
        __shared__ float part[4][NB];
        const int w = t >> 6, l = t & 63;
        if (l == 0) {
            #pragma unroll
            for (int k = 0; k < NB; ++k) part[w][k] = p[k];
        }
        __syncthreads();
        if (t < NB) bs[t] = part[0][t] + part[1][t] + part[2][t] + part[3][t];

        // probe: odd int32 slots of the first 64 int64 slots (coalesced wave load)
        if (w == 1) {
            int v = eidx[2 * l + 1];
            unsigned long long any = __ballot(v != 0);
            if (l == 0) *flag = any ? 1 : 2;
        }
        return;
    }

    // ---- proj block: 64 nodes, 4 threads per node ----
    const int part_id = t & 3;             // dim quarter
    const int n = blockIdx.x * 64 + (t >> 2);
    if (n >= n_nodes) return;

    const float4* __restrict__ xr =
        (const float4*)(x + (size_t)n * IN_DIM + part_id * 32);

    float acc[12];
    #pragma unroll
    for (int j = 0; j < 12; ++j) acc[j] = 0.f;

    #pragma unroll
    for (int q = 0; q < 8; ++q) {
        float4 v = xr[q];
        #pragma unroll
        for (int j = 0; j < 12; ++j) {
            // output j -> weight row (compile-time after unroll, wave-uniform-ish)
            const float* __restrict__ wrow =
                (j < 5)  ? (attn_w + j * 256)
              : (j == 5) ? scorer_w
              : (j < 11) ? (attn_w + (j - 6) * 256 + IN_DIM)
                         : (scorer_w + IN_DIM);
            float4 wv = *(const float4*)(wrow + part_id * 32 + q * 4);
            acc[j] = fmaf(v.x, wv.x, fmaf(v.y, wv.y,
                     fmaf(v.z, wv.z, fmaf(v.w, wv.w, acc[j]))));
        }
    }

    // reduce the 4 dim-quarters (lanes t^1, t^2)
    #pragma unroll
    for (int j = 0; j < 12; ++j) {
        acc[j] += __shfl_xor(acc[j], 1, 64);
        acc[j] += __shfl_xor(acc[j], 2, 64);
    }

    if (part_id == 0) {
        float4* __restrict__ sr = (float4*)(srcTab + (size_t)n * 8);
        float4* __restrict__ dr = (float4*)(dstTab + (size_t)n * 8);
        sr[0] = make_float4(acc[0], acc[1], acc[2], acc[3]);
        sr[1] = make_float4(acc[4], acc[5], 0.f, 0.f);
        dr[0] = make_float4(acc[6], acc[7], acc[8], acc[9]);
        dr[1] = make_float4(acc[10], acc[11], 0.f, 0.f);
    }
}

// ---------------------------------------------------------------------------
// K2: per-edge attention + scorer, 2 edges per thread
// ---------------------------------------------------------------------------
__global__ __launch_bounds__(256) void edge_kernel(
    const int*   __restrict__ eidx,
    const float* __restrict__ ew,
    const float* __restrict__ attn_b,     // [5]
    const float* __restrict__ scorer_b,   // [1]
    const float* __restrict__ srcTab,     // [N][8]
    const float* __restrict__ dstTab,     // [N][8]
    const float* __restrict__ bs,         // [5]
    const int*   __restrict__ flag,
    float* __restrict__ out,
    int n_edges)
{
    const int stride = *flag;  // uniform
    const float b0 = attn_b[0], b1 = attn_b[1], b2 = attn_b[2],
                b3 = attn_b[3], b4 = attn_b[4];
    const float sb = scorer_b[0];
    const float s0 = bs[0], s1 = bs[1], s2 = bs[2], s3 = bs[3], s4 = bs[4];

    const int e0 = (blockIdx.x * blockDim.x + threadIdx.x) * 2;
    if (e0 >= n_edges) return;
    const bool has2 = (e0 + 1 < n_edges);

    int src0, dst0, src1, dst1;
    if (stride == 1) {
        if (((n_edges | e0) & 1) == 0) {
            int2 sp = *(const int2*)(eidx + e0);
            int2 dp = *(const int2*)(eidx + n_edges + e0);
            src0 = sp.x; src1 = sp.y; dst0 = dp.x; dst1 = dp.y;
        } else {
            src0 = eidx[e0];            src1 = has2 ? eidx[e0 + 1] : 0;
            dst0 = eidx[n_edges + e0];  dst1 = has2 ? eidx[n_edges + e0 + 1] : 0;
        }
    } else {
        if (((n_edges | e0) & 1) == 0) {
            int4 sp = *(const int4*)(eidx + 2 * (size_t)e0);
            int4 dp = *(const int4*)(eidx + 2 * ((size_t)n_edges + e0));
            src0 = sp.x; src1 = sp.z; dst0 = dp.x; dst1 = dp.z;
        } else {
            src0 = eidx[2 * (size_t)e0];
            src1 = has2 ? eidx[2 * ((size_t)e0 + 1)] : 0;
            dst0 = eidx[2 * ((size_t)n_edges + e0)];
            dst1 = has2 ? eidx[2 * ((size_t)n_edges + e0 + 1)] : 0;
        }
    }

    // issue all gathers up-front (ILP)
    const float4* __restrict__ ps0 = (const float4*)(srcTab + (size_t)src0 * 8);
    const float4* __restrict__ pd0 = (const float4*)(dstTab + (size_t)dst0 * 8);
    const float4* __restrict__ ps1 = (const float4*)(srcTab + (size_t)src1 * 8);
    const float4* __restrict__ pd1 = (const float4*)(dstTab + (size_t)dst1 * 8);
    float4 a0 = ps0[0], a1 = ps0[1];
    float4 c0 = pd0[0], c1 = pd0[1];
    float4 A0 = ps1[0], A1 = ps1[1];
    float4 C0 = pd1[0], C1 = pd1[1];

    float w0, w1 = 0.f;
    if (has2 && ((e0 & 1) == 0)) {
        float2 wv = *(const float2*)(ew + e0);
        w0 = wv.x; w1 = wv.y;
    } else {
        w0 = ew[e0];
        if (has2) w1 = ew[e0 + 1];
    }

    auto score = [&](float4 a0_, float4 a1_, float4 c0_, float4 c1_) -> float {
        float l0 = a0_.x + c0_.x + b0;
        float l1 = a0_.y + c0_.y + b1;
        float l2 = a0_.z + c0_.z + b2;
        float l3 = a0_.w + c0_.w + b3;
        float l4 = a1_.x + c1_.x + b4;
        float lsc = a1_.y + c1_.y;
        float m = fmaxf(fmaxf(fmaxf(l0, l1), fmaxf(l2, l3)), l4);
        float e0_ = __expf(l0 - m);
        float e1_ = __expf(l1 - m);
        float e2_ = __expf(l2 - m);
        float e3_ = __expf(l3 - m);
        float e4_ = __expf(l4 - m);
        float inv = 1.f / (e0_ + e1_ + e2_ + e3_ + e4_);
        float mix = (e0_ * s0 + e1_ * s1 + e2_ * s2 + e3_ * s3 + e4_ * s4) * inv;
        float logit = lsc + mix + sb;
        return 1.f / (1.f + __expf(-logit));
    };

    float r0 = w0 * score(a0, a1, c0, c1);
    float r1 = has2 ? (w1 * score(A0, A1, C0, C1)) : 0.f;

    if (has2 && ((e0 & 1) == 0)) {
        *(float2*)(out + e0) = make_float2(r0, r1);
    } else {
        out[e0] = r0;
        if (has2) out[e0 + 1] = r1;
    }
}

// ---------------------------------------------------------------------------
extern "C" void kernel_launch(void* const* d_in, const int* in_sizes, int n_in,
                              void* d_out, int out_size, void* d_ws, size_t ws_size,
                              hipStream_t stream) {
    const float* x        = (const float*)d_in[0];
    const int*   eidx     = (const int*)  d_in[1];
    const float* ew       = (const float*)d_in[2];
    const float* bases    = (const float*)d_in[3];
    const float* attn_w   = (const float*)d_in[4];
    const float* attn_b   = (const float*)d_in[5];
    const float* scorer_w = (const float*)d_in[6];
    const float* scorer_b = (const float*)d_in[7];
    float* out = (float*)d_out;

    const int n_nodes = in_sizes[0] / IN_DIM;
    const int n_edges = in_sizes[2];

    // workspace layout (16-float aligned)
    int*   flag   = (int*)d_ws;                            // offset 0
    float* bs     = (float*)d_ws + 16;                     // offset 64 B
    float* srcTab = (float*)d_ws + 64;                     // [N][8]
    float* dstTab = srcTab + (size_t)n_nodes * 8;          // [N][8]

    const int pblocks = (n_nodes + 63) / 64;
    proj_prep_kernel<<<pblocks + 1, 256, 0, stream>>>(
        x, attn_w, scorer_w, bases, eidx, srcTab, dstTab, bs, flag, n_nodes);

    const int eblocks = ((n_edges + 1) / 2 + 255) / 256;
    edge_kernel<<<eblocks, 256, 0, stream>>>(
        eidx, ew, attn_b, scorer_b, srcTab, dstTab, bs, flag, out, n_edges);
}

// Round 3
// 106.472 us; speedup vs baseline: 1.3128x; 1.3128x over previous
//
#include <hip/hip_runtime.h>

#define IN_DIM 128
#define NB 5

// ---------------------------------------------------------------------------
// K1: per-node projection tables (+ basis scores + index-width probe).
//   srcTab[n][0..4] = x[n].attn_w[k][0:128],   [5] = x[n].scorer_w[0:128]
//   dstTab[n][0..4] = x[n].attn_w[k][128:256], [5] = x[n].scorer_w[128:256]
// Rows are 32 B (8 floats; 6,7 pad).
// Block = 256 threads = 4 waves; block covers 64 nodes. Wave w handles dim
// quarter w (32 dims) for all 64 nodes (lane = node). Weight addresses are
// wave-uniform -> scalar s_load (no per-lane VMEM, no L1 thrash).
// Per-thread VMEM: just 8 independent float4 x-loads, pre-issued.
// Cross-wave (cross-quarter) reduce via padded LDS.
// ---------------------------------------------------------------------------
__global__ __launch_bounds__(256) void proj_prep_kernel(
    const float* __restrict__ x,          // [N][128]
    const float* __restrict__ attn_w,     // [5][256]
    const float* __restrict__ scorer_w,   // [256]
    const float* __restrict__ bases,      // [5][256]
    const int*   __restrict__ eidx,       // index buffer viewed as int32
    float* __restrict__ srcTab,           // [N][8]
    float* __restrict__ dstTab,           // [N][8]
    float* __restrict__ bs,               // [5]
    int*   __restrict__ flag,             // stride (1 or 2)
    int n_nodes)
{
    const int t = threadIdx.x;

    if (blockIdx.x == gridDim.x - 1) {
        // ---- prep block: bs[k] = dot(bases[k], scorer_w); index-width probe
        float p[NB];
        #pragma unroll
        for (int k = 0; k < NB; ++k)
            p[k] = bases[k * 256 + t] * scorer_w[t];
        #pragma unroll
        for (int k = 0; k < NB; ++k) {
            #pragma unroll
            for (int off = 32; off > 0; off >>= 1)
                p[k] += __shfl_xor(p[k], off, 64);
        }
        __shared__ float part_s[4][NB];
        const int w = t >> 6, l = t & 63;
        if (l == 0) {
            #pragma unroll
            for (int k = 0; k < NB; ++k) part_s[w][k] = p[k];
        }
        __syncthreads();
        if (t < NB) bs[t] = part_s[0][t] + part_s[1][t] + part_s[2][t] + part_s[3][t];

        if (w == 1) {
            int v = eidx[2 * l + 1];   // odd int32 slots of first 64 int64 entries
            unsigned long long any = __ballot(v != 0);
            if (l == 0) *flag = any ? 1 : 2;
        }
        return;
    }

    const int lane = t & 63;
    const int part = __builtin_amdgcn_readfirstlane(t >> 6);   // 0..3, wave-uniform
    const int n = blockIdx.x * 64 + lane;

    // wave-uniform weight-slice base pointers (quarter `part`, 32 dims each)
    const float* __restrict__ wb0  = attn_w + 0 * 256 + part * 32;
    const float* __restrict__ wb1  = attn_w + 1 * 256 + part * 32;
    const float* __restrict__ wb2  = attn_w + 2 * 256 + part * 32;
    const float* __restrict__ wb3  = attn_w + 3 * 256 + part * 32;
    const float* __restrict__ wb4  = attn_w + 4 * 256 + part * 32;
    const float* __restrict__ wb5  = scorer_w + part * 32;
    const float* __restrict__ wb6  = attn_w + 0 * 256 + 128 + part * 32;
    const float* __restrict__ wb7  = attn_w + 1 * 256 + 128 + part * 32;
    const float* __restrict__ wb8  = attn_w + 2 * 256 + 128 + part * 32;
    const float* __restrict__ wb9  = attn_w + 3 * 256 + 128 + part * 32;
    const float* __restrict__ wb10 = attn_w + 4 * 256 + 128 + part * 32;
    const float* __restrict__ wb11 = scorer_w + 128 + part * 32;
    const float* __restrict__ wb[12] = {wb0, wb1, wb2,  wb3, wb4,  wb5,
                                        wb6, wb7, wb8, wb9, wb10, wb11};

    float acc[12];
    #pragma unroll
    for (int j = 0; j < 12; ++j) acc[j] = 0.f;

    if (n < n_nodes) {
        const float4* __restrict__ xr =
            (const float4*)(x + (size_t)n * IN_DIM + part * 32);
        float4 xv[8];
        #pragma unroll
        for (int q = 0; q < 8; ++q) xv[q] = xr[q];   // 8 independent loads, pipelined

        #pragma unroll
        for (int q = 0; q < 8; ++q) {
            float4 v = xv[q];
            #pragma unroll
            for (int j = 0; j < 12; ++j) {
                float4 wv = *(const float4*)(wb[j] + q * 4);   // uniform -> s_load
                acc[j] = fmaf(v.x, wv.x, fmaf(v.y, wv.y,
                         fmaf(v.z, wv.z, fmaf(v.w, wv.w, acc[j]))));
            }
        }
    }

    // cross-wave reduce: [part][node][j], inner dim padded to 13 (odd -> no bank clash)
    __shared__ float red[4][64][13];
    #pragma unroll
    for (int j = 0; j < 12; ++j) red[part][lane][j] = acc[j];
    __syncthreads();

    // 64 nodes x 12 outputs = 768 values; each of 256 threads sums 3
    #pragma unroll
    for (int k = 0; k < 3; ++k) {
        int s = t + k * 256;
        int node = s / 12, j = s - node * 12;
        float v = red[0][node][j] + red[1][node][j] + red[2][node][j] + red[3][node][j];
        int nn = blockIdx.x * 64 + node;
        if (nn < n_nodes) {
            if (j < 6) srcTab[(size_t)nn * 8 + j]       = v;
            else       dstTab[(size_t)nn * 8 + (j - 6)] = v;
        }
    }
}

// ---------------------------------------------------------------------------
// K2: per-edge attention + scorer, 1 edge/thread (max TLP, min VGPR)
// ---------------------------------------------------------------------------
__global__ __launch_bounds__(256) void edge_kernel(
    const int*   __restrict__ eidx,
    const float* __restrict__ ew,
    const float* __restrict__ attn_b,     // [5]
    const float* __restrict__ scorer_b,   // [1]
    const float* __restrict__ srcTab,     // [N][8]
    const float* __restrict__ dstTab,     // [N][8]
    const float* __restrict__ bs,         // [5]
    const int*   __restrict__ flag,
    float* __restrict__ out,
    int n_edges)
{
    const int e = blockIdx.x * 256 + threadIdx.x;
    if (e >= n_edges) return;

    const int stride = *flag;   // uniform scalar branch
    int src, dst;
    if (stride == 2) {
        src = eidx[2 * (size_t)e];
        dst = eidx[2 * ((size_t)n_edges + e)];
    } else {
        src = eidx[e];
        dst = eidx[(size_t)n_edges + e];
    }

    // issue all gathers + ew up-front
    const float4* __restrict__ ps = (const float4*)(srcTab + (size_t)src * 8);
    const float4* __restrict__ pd = (const float4*)(dstTab + (size_t)dst * 8);
    float4 a0 = ps[0], a1 = ps[1];
    float4 c0 = pd[0], c1 = pd[1];
    float w = ew[e];

    const float b0 = attn_b[0], b1 = attn_b[1], b2 = attn_b[2],
                b3 = attn_b[3], b4 = attn_b[4];
    const float sb = scorer_b[0];
    const float s0 = bs[0], s1 = bs[1], s2 = bs[2], s3 = bs[3], s4 = bs[4];

    float l0 = a0.x + c0.x + b0;
    float l1 = a0.y + c0.y + b1;
    float l2 = a0.z + c0.z + b2;
    float l3 = a0.w + c0.w + b3;
    float l4 = a1.x + c1.x + b4;
    float lsc = a1.y + c1.y;             // edge_feats . scorer_w

    float m = fmaxf(fmaxf(fmaxf(l0, l1), fmaxf(l2, l3)), l4);
    float e0 = __expf(l0 - m);
    float e1 = __expf(l1 - m);
    float e2 = __expf(l2 - m);
    float e3 = __expf(l3 - m);
    float e4 = __expf(l4 - m);
    float inv = 1.f / (e0 + e1 + e2 + e3 + e4);

    float mix = (e0 * s0 + e1 * s1 + e2 * s2 + e3 * s3 + e4 * s4) * inv;
    float logit = lsc + mix + sb;
    float sc = 1.f / (1.f + __expf(-logit));
    out[e] = w * sc;
}

// ---------------------------------------------------------------------------
extern "C" void kernel_launch(void* const* d_in, const int* in_sizes, int n_in,
                              void* d_out, int out_size, void* d_ws, size_t ws_size,
                              hipStream_t stream) {
    const float* x        = (const float*)d_in[0];
    const int*   eidx     = (const int*)  d_in[1];
    const float* ew       = (const float*)d_in[2];
    const float* bases    = (const float*)d_in[3];
    const float* attn_w   = (const float*)d_in[4];
    const float* attn_b   = (const float*)d_in[5];
    const float* scorer_w = (const float*)d_in[6];
    const float* scorer_b = (const float*)d_in[7];
    float* out = (float*)d_out;

    const int n_nodes = in_sizes[0] / IN_DIM;
    const int n_edges = in_sizes[2];

    // workspace layout
    int*   flag   = (int*)d_ws;                            // offset 0
    float* bs     = (float*)d_ws + 16;                     // offset 64 B
    float* srcTab = (float*)d_ws + 64;                     // [N][8]
    float* dstTab = srcTab + (size_t)n_nodes * 8;          // [N][8]

    const int pblocks = (n_nodes + 63) / 64;
    proj_prep_kernel<<<pblocks + 1, 256, 0, stream>>>(
        x, attn_w, scorer_w, bases, eidx, srcTab, dstTab, bs, flag, n_nodes);

    const int eblocks = (n_edges + 255) / 256;
    edge_kernel<<<eblocks, 256, 0, stream>>>(
        eidx, ew, attn_b, scorer_b, srcTab, dstTab, bs, flag, out, n_edges);
}